// Round 3
// baseline (803.650 us; speedup 1.0000x reference)
//
#include <hip/hip_runtime.h>
#include <hip/hip_fp16.h>

#define T_SEQ 2048
#define HID   50
#define KP    64      // k: 0..49 = h, 50..62 = onehot, 63 = bias
#define MB    8       // batch rows per block (8 real rows per MFMA tile, x2 dup)
#define NBLK  256     // 2048 / MB -> 1 block/CU
#define NTHR  256     // 4 waves
#define HSTR  80      // ushorts per h row (160 B)
#define BUFB  (MB*HSTR)   // ushorts per buffer = 640

typedef __attribute__((ext_vector_type(8))) _Float16 half8;
typedef __attribute__((ext_vector_type(4))) float    f32x4;

__device__ __forceinline__ ushort f16b(float f){ return __half_as_ushort(__float2half(f)); }
__device__ __forceinline__ float rcp_(float x){ return __builtin_amdgcn_rcpf(x); }
__device__ __forceinline__ float sigm(float x){ return rcp_(1.f + __expf(-x)); }
__device__ __forceinline__ float tanh_(float x){ return fmaf(2.f, rcp_(1.f + __expf(-2.f*x)), -1.f); }

// Bm[256 cols][64 k] f16.  col = w*64 + g*16 + c16 encodes unit u = w*16+c16, gate g.
// Row r = g*50+u:  k<50: W_hh[r][k];  k in 50..62: embed[k-50]·W_ih[r] (onehot folded
// into K);  k==63: b_ih[r]+b_hh[r];  pad cols (u>=50) zero.
__global__ void build_B(const float* __restrict__ embed, const float* __restrict__ Wih,
                        const float* __restrict__ Whh, const float* __restrict__ bih,
                        const float* __restrict__ bhh, ushort* __restrict__ Bm) {
    int idx = blockIdx.x * blockDim.x + threadIdx.x;
    if (idx >= 256 * KP) return;
    int col = idx >> 6, k = idx & 63;
    int wq = col >> 6, g = (col >> 4) & 3, cc = col & 15;
    int u = wq * 16 + cc;
    ushort v = 0;
    if (u < HID) {
        int r = g * HID + u;
        if (k < HID) {
            v = f16b(Whh[r * HID + k]);
        } else if (k < 63) {
            float s = 0.f;
            for (int e = 0; e < HID; ++e)
                s = fmaf(embed[(k - 50) * HID + e], Wih[r * HID + e], s);
            v = f16b(s);
        } else {
            v = f16b(bih[r] + bhh[r]);
        }
    }
    Bm[idx] = v;
}

// MB=8 rows/block, 4 waves, 1 block/CU. A rows = h[row&7] (dup x2): lane (q,c16) holds
// batch rows 4q+reg mod 8 -> q covers row pairs {0,1},{4,5},{2,3},{6,7} via (q&2) select.
// 2 activations/lane, 8 cndmask, half the MFMA issue of MB=4. 1 barrier/step.
__global__ __launch_bounds__(NTHR, 1) void lstm8(
    const int*    __restrict__ x,
    const ushort* __restrict__ Bm,
    const float*  __restrict__ W1,
    const float*  __restrict__ b1,
    const float*  __restrict__ W2,
    const float*  __restrict__ b2,
    float*        __restrict__ out)
{
    const int t   = threadIdx.x;
    const int w   = t >> 6;
    const int l   = t & 63;
    const int q   = l >> 4;
    const int c16 = l & 15;
    const int u   = w * 16 + c16;            // unit handled by this lane
    const int r0  = (q & 2) + 4 * (q & 1);   // first of the lane's two batch rows

    __shared__ __align__(16) ushort hbuf[2 * BUFB];   // 2560 B
    __shared__ float zb[HID * MB];                    // 1600 B

    // B fragments: wave w owns tiles 4w..4w+3 (gate j), col c16. Order: f,i,g,o issue
    // order below so the c-chain starts before all MFMAs retire.
    half8 bf[4][2];
    {
        const ushort* bp = Bm + (w * 64 + c16) * KP + q * 8;
        #pragma unroll
        for (int j = 0; j < 4; ++j) {
            bf[j][0] = *(const half8*)(bp + j * 16 * KP);
            bf[j][1] = *(const half8*)(bp + j * 16 * KP + 32);
        }
    }
    #pragma unroll
    for (int j = 0; j < 4; ++j)
        asm volatile("" : "+v"(bf[j][0]), "+v"(bf[j][1]));

    for (int i = t; i < 2 * BUFB; i += NTHR) hbuf[i] = 0;

    const int  row0 = blockIdx.x * MB;
    const long xb   = (long)row0 * T_SEQ;
    int t0r = 0, t1r = 0, t2r = 0;
    __syncthreads();
    if (t < MB) {
        int tk0 = x[xb + (long)t * T_SEQ + 0];
        int tk1 = x[xb + (long)t * T_SEQ + 1];
        hbuf[0 * BUFB + t * HSTR + 63] = 0x3C00;        // bias slot = 1.0
        hbuf[1 * BUFB + t * HSTR + 63] = 0x3C00;
        hbuf[0 * BUFB + t * HSTR + 50 + tk0] = 0x3C00;  // onehot step 0
        hbuf[1 * BUFB + t * HSTR + 50 + tk1] = 0x3C00;  // onehot step 1
        t0r = tk1; t1r = tk0; t2r = tk1;                // clear(t-1)/set(t+1) window
    }
    __syncthreads();

    // A-frag read: A[c16, 8q..8q+7] = h[c16&7][8q..]; lanes c16, c16+8 broadcast.
    const ushort* ar  = hbuf + (c16 & 7) * HSTR + q * 8;
    ushort*       wr_ = hbuf + r0 * HSTR + u;           // h writes: rows r0, r0+1

    float c0 = 0.f, c1 = 0.f;

#define STEP(P) do {                                                              \
        int pf = 0;                                                               \
        if (t < MB) {                                                             \
            int it = step + 2 + (P); if (it > T_SEQ - 1) it = T_SEQ - 1;          \
            pf = x[xb + (long)t * T_SEQ + it];                                    \
        }                                                                         \
        half8 a0 = *(const half8*)(ar + (P) * BUFB);                              \
        half8 a1 = *(const half8*)(ar + (P) * BUFB + 32);                         \
        const f32x4 zz = {0.f, 0.f, 0.f, 0.f};                                    \
        f32x4 z1 = __builtin_amdgcn_mfma_f32_16x16x32_f16(a0, bf[1][0], zz,0,0,0);\
        z1 = __builtin_amdgcn_mfma_f32_16x16x32_f16(a1, bf[1][1], z1, 0,0,0);     \
        f32x4 z0 = __builtin_amdgcn_mfma_f32_16x16x32_f16(a0, bf[0][0], zz,0,0,0);\
        z0 = __builtin_amdgcn_mfma_f32_16x16x32_f16(a1, bf[0][1], z0, 0,0,0);     \
        f32x4 z2 = __builtin_amdgcn_mfma_f32_16x16x32_f16(a0, bf[2][0], zz,0,0,0);\
        z2 = __builtin_amdgcn_mfma_f32_16x16x32_f16(a1, bf[2][1], z2, 0,0,0);     \
        f32x4 z3 = __builtin_amdgcn_mfma_f32_16x16x32_f16(a0, bf[3][0], zz,0,0,0);\
        z3 = __builtin_amdgcn_mfma_f32_16x16x32_f16(a1, bf[3][1], z3, 0,0,0);     \
        bool hi = (q & 2) != 0;                                                   \
        float vf_a = hi ? z1[2] : z1[0], vf_b = hi ? z1[3] : z1[1];               \
        float vi_a = hi ? z0[2] : z0[0], vi_b = hi ? z0[3] : z0[1];               \
        float vg_a = hi ? z2[2] : z2[0], vg_b = hi ? z2[3] : z2[1];               \
        float vo_a = hi ? z3[2] : z3[0], vo_b = hi ? z3[3] : z3[1];               \
        float f0 = sigm(vf_a), i0 = sigm(vi_a), g0 = tanh_(vg_a), o0 = sigm(vo_a);\
        float f1 = sigm(vf_b), i1 = sigm(vi_b), g1 = tanh_(vg_b), o1 = sigm(vo_b);\
        c0 = fmaf(f0, c0, i0 * g0);                                               \
        c1 = fmaf(f1, c1, i1 * g1);                                               \
        float h0 = o0 * tanh_(c0);                                                \
        float h1 = o1 * tanh_(c1);                                                \
        if (u < HID) {                                                            \
            wr_[(1 - (P)) * BUFB] = f16b(h0);                                     \
            wr_[(1 - (P)) * BUFB + HSTR] = f16b(h1);                              \
        }                                                                         \
        if (t < MB) {                                                             \
            ushort* hb = hbuf + (1 - (P)) * BUFB + t * HSTR + 50;                 \
            hb[t0r] = 0;                                                          \
            hb[t2r] = 0x3C00;                                                     \
            t0r = t1r; t1r = t2r; t2r = pf;                                       \
        }                                                                         \
        __syncthreads();                                                          \
    } while (0)

    #pragma unroll 1
    for (int step = 0; step < T_SEQ; step += 2) {
        STEP(0);
        STEP(1);
    }
#undef STEP

    // Epilogue MLP: final h in buffer 0 (last step wrote it), already synced.
    for (int idx = t; idx < MB * HID; idx += NTHR) {
        int m = idx & 7, uu = idx >> 3;
        float a = b1[uu];
        const ushort* hr = hbuf + m * HSTR;
        #pragma unroll 10
        for (int k = 0; k < HID; ++k)
            a = fmaf(W1[uu * HID + k], __half2float(__ushort_as_half(hr[k])), a);
        zb[uu * MB + m] = fmaxf(a, 0.f);
    }
    __syncthreads();
    if (t < MB) {
        float a = b2[0];
        #pragma unroll 10
        for (int j = 0; j < HID; ++j)
            a = fmaf(W2[j], zb[j * MB + t], a);
        out[row0 + t] = a;
    }
}

extern "C" void kernel_launch(void* const* d_in, const int* in_sizes, int n_in,
                              void* d_out, int out_size, void* d_ws, size_t ws_size,
                              hipStream_t stream) {
    const int*   x     = (const int*)  d_in[0];
    const float* embed = (const float*)d_in[1];
    const float* W_ih  = (const float*)d_in[2];
    const float* W_hh  = (const float*)d_in[3];
    const float* b_ih  = (const float*)d_in[4];
    const float* b_hh  = (const float*)d_in[5];
    const float* W1    = (const float*)d_in[6];
    const float* b1    = (const float*)d_in[7];
    const float* W2    = (const float*)d_in[8];
    const float* b2    = (const float*)d_in[9];
    float* out = (float*)d_out;

    ushort* Bm = (ushort*)d_ws;   // 256*64*2 = 32768 B scratch

    build_B<<<(256 * KP + NTHR - 1) / NTHR, NTHR, 0, stream>>>(
        embed, W_ih, W_hh, b_ih, b_hh, Bm);

    lstm8<<<NBLK, NTHR, 0, stream>>>(
        x, Bm, W1, b1, W2, b2, out);
}

// Round 4
// 707.566 us; speedup vs baseline: 1.1358x; 1.1358x over previous
//
#include <hip/hip_runtime.h>
#include <hip/hip_fp16.h>

#define T_SEQ 2048
#define HID   50
#define KP    64      // k: 0..49 = h, 50..62 = onehot, 63 = bias
#define MB    4       // batch rows per block
#define NBLK  512     // 2048 / MB -> 2 blocks/CU (proven overlap regime)
#define NTHR  256     // 4 waves
#define HSTR  80      // ushorts per h row (160 B)
#define BUFB  (MB*HSTR)

#define NLOG2E  1.4426950408889634f   // gates scaled by -log2e (g-gate by -2log2e) in B
#define N2LOG2E 2.8853900817779268f

typedef __attribute__((ext_vector_type(8))) _Float16 half8;
typedef __attribute__((ext_vector_type(4))) float    f32x4;

__device__ __forceinline__ ushort f16b(float f){ return __half_as_ushort(__float2half(f)); }
__device__ __forceinline__ float rcp_(float x){ return __builtin_amdgcn_rcpf(x); }
__device__ __forceinline__ float ex2_(float x){ return __builtin_amdgcn_exp2f(x); }

// Bm[256 cols][64 k] f16.  col = w*64 + g*16 + c16 encodes unit u = w*16+c16, gate g
// (g: 0=i,1=f,2=g,3=o).  Row r = g*50+u.  ALL entries pre-scaled by -log2e (g-gate
// by -2log2e) so the MFMA emits gates in exp2 domain:
//   k<50: s*W_hh[r][k];  k in 50..62: s*embed[k-50]·W_ih[r];  k==63: s*(b_ih+b_hh)[r].
__global__ void build_B(const float* __restrict__ embed, const float* __restrict__ Wih,
                        const float* __restrict__ Whh, const float* __restrict__ bih,
                        const float* __restrict__ bhh, ushort* __restrict__ Bm) {
    int idx = blockIdx.x * blockDim.x + threadIdx.x;
    if (idx >= 256 * KP) return;
    int col = idx >> 6, k = idx & 63;
    int wq = col >> 6, g = (col >> 4) & 3, cc = col & 15;
    int u = wq * 16 + cc;
    ushort v = 0;
    if (u < HID) {
        int r = g * HID + u;
        float s = (g == 2) ? -N2LOG2E : -NLOG2E;
        if (k < HID) {
            v = f16b(s * Whh[r * HID + k]);
        } else if (k < 63) {
            float t = 0.f;
            for (int e = 0; e < HID; ++e)
                t = fmaf(embed[(k - 50) * HID + e], Wih[r * HID + e], t);
            v = f16b(s * t);
        } else {
            v = f16b(s * (bih[r] + bhh[r]));
        }
    }
    Bm[idx] = v;
}

// MB=4, 4 waves, 2 blocks/CU. A rows = h[m>>2] (consecutive dup): lane quadrant q's
// accumulator regs ALL hold batch row q -> z[0] direct, zero selects. Gates arrive
// exp2-scaled; fused activation: 5 exp2 + 2 rcp per set (was 10 trans).
__global__ __launch_bounds__(NTHR, 2) void lstm4(
    const int*    __restrict__ x,
    const ushort* __restrict__ Bm,
    const float*  __restrict__ W1,
    const float*  __restrict__ b1,
    const float*  __restrict__ W2,
    const float*  __restrict__ b2,
    float*        __restrict__ out)
{
    const int t   = threadIdx.x;
    const int w   = t >> 6;
    const int l   = t & 63;
    const int q   = l >> 4;
    const int c16 = l & 15;
    const int u   = w * 16 + c16;          // unit handled by this lane (batch row q)

    __shared__ __align__(16) ushort hbuf[2 * BUFB];   // 1280 B
    __shared__ float zb[HID * MB];

    // B fragments: wave w owns tiles 4w..4w+3 (gate j), col c16
    half8 bf[4][2];
    {
        const ushort* bp = Bm + (w * 64 + c16) * KP + q * 8;
        #pragma unroll
        for (int j = 0; j < 4; ++j) {
            bf[j][0] = *(const half8*)(bp + j * 16 * KP);
            bf[j][1] = *(const half8*)(bp + j * 16 * KP + 32);
        }
    }
    #pragma unroll
    for (int j = 0; j < 4; ++j)
        asm volatile("" : "+v"(bf[j][0]), "+v"(bf[j][1]));

    for (int i = t; i < 2 * BUFB; i += NTHR) hbuf[i] = 0;

    const int  row0 = blockIdx.x * MB;
    const long xb   = (long)row0 * T_SEQ;
    int t0r = 0, t1r = 0, t2r = 0;
    __syncthreads();
    if (l == 0) {                           // wave w maintains batch row w's token
        int tk0 = x[xb + (long)w * T_SEQ + 0];
        int tk1 = x[xb + (long)w * T_SEQ + 1];
        hbuf[0 * BUFB + w * HSTR + 63] = 0x3C00;        // bias slot = 1.0
        hbuf[1 * BUFB + w * HSTR + 63] = 0x3C00;
        hbuf[0 * BUFB + w * HSTR + 50 + tk0] = 0x3C00;  // onehot step 0
        hbuf[1 * BUFB + w * HSTR + 50 + tk1] = 0x3C00;  // onehot step 1
        t0r = tk1; t1r = tk0; t2r = tk1;                // clear(t-1)/set(t+1) window
    }
    __syncthreads();

    // A row m = h[m>>2]: quadrant lanes 4-lane-broadcast, 2-way banks = free
    const ushort* ar  = hbuf + (c16 >> 2) * HSTR + q * 8;
    ushort*       wr_ = hbuf + q * HSTR + u;            // h write: row q, unit u

    float cst = 0.f;

#define STEP(P) do {                                                              \
        int tknf = 0;                                                             \
        if (l == 0) {                                                             \
            int it = step + 2 + (P); if (it > T_SEQ - 1) it = T_SEQ - 1;          \
            tknf = x[xb + (long)w * T_SEQ + it];                                  \
        }                                                                         \
        half8 a0 = *(const half8*)(ar + (P) * BUFB);                              \
        half8 a1 = *(const half8*)(ar + (P) * BUFB + 32);                         \
        const f32x4 zz = {0.f, 0.f, 0.f, 0.f};                                    \
        __builtin_amdgcn_s_setprio(1);                                            \
        f32x4 z0 = __builtin_amdgcn_mfma_f32_16x16x32_f16(a0, bf[0][0], zz,0,0,0);\
        z0 = __builtin_amdgcn_mfma_f32_16x16x32_f16(a1, bf[0][1], z0, 0,0,0);     \
        f32x4 z1 = __builtin_amdgcn_mfma_f32_16x16x32_f16(a0, bf[1][0], zz,0,0,0);\
        z1 = __builtin_amdgcn_mfma_f32_16x16x32_f16(a1, bf[1][1], z1, 0,0,0);     \
        f32x4 z2 = __builtin_amdgcn_mfma_f32_16x16x32_f16(a0, bf[2][0], zz,0,0,0);\
        z2 = __builtin_amdgcn_mfma_f32_16x16x32_f16(a1, bf[2][1], z2, 0,0,0);     \
        f32x4 z3 = __builtin_amdgcn_mfma_f32_16x16x32_f16(a0, bf[3][0], zz,0,0,0);\
        z3 = __builtin_amdgcn_mfma_f32_16x16x32_f16(a1, bf[3][1], z3, 0,0,0);     \
        __builtin_amdgcn_s_setprio(0);                                            \
        /* z = -log2e*gate (g: -2log2e). clamp high side only: 2^30 caps products */\
        float pi = ex2_(fminf(z0[0], 30.f));   /* e^-gi  */                       \
        float pf = ex2_(fminf(z1[0], 30.f));   /* e^-gf  */                       \
        float qg = ex2_(fminf(z2[0], 30.f));   /* e^-2gg */                       \
        float Df = 1.f + pf;                                                      \
        float D2 = (1.f + pi) * (1.f + qg);                                       \
        float iv1 = rcp_(Df * D2);                                                \
        float fv  = iv1 * D2;                  /* sigm(gf) */                     \
        float ig  = iv1 * Df * (1.f - qg);     /* sigm(gi)*tanh(gg) */            \
        cst = fmaf(fv, cst, ig);                                                  \
        float po = ex2_(fminf(z3[0], 30.f));   /* e^-go  */                       \
        float qc = ex2_(fminf(cst * -N2LOG2E, 30.f));  /* e^-2c */                \
        float iv2 = rcp_((1.f + po) * (1.f + qc));                                \
        float hh  = iv2 * (1.f - qc);          /* sigm(go)*tanh(c) */             \
        if (u < HID) wr_[(1 - (P)) * BUFB] = f16b(hh);                            \
        if (l == 0) {                                                             \
            ushort* hb = hbuf + (1 - (P)) * BUFB + w * HSTR + 50;                 \
            hb[t0r] = 0;                                                          \
            hb[t2r] = 0x3C00;                                                     \
            t0r = t1r; t1r = t2r; t2r = tknf;                                     \
        }                                                                         \
        __syncthreads();                                                          \
    } while (0)

    #pragma unroll 1
    for (int step = 0; step < T_SEQ; step += 2) {
        STEP(0);
        STEP(1);
    }
#undef STEP

    // Epilogue MLP: final h in buffer 0 (last step wrote it), already synced.
    if (t < MB * HID) {
        int m = t & 3, uu = t >> 2;
        float a = b1[uu];
        const ushort* hr = hbuf + m * HSTR;
        #pragma unroll 10
        for (int k = 0; k < HID; ++k)
            a = fmaf(W1[uu * HID + k], __half2float(__ushort_as_half(hr[k])), a);
        zb[uu * MB + m] = fmaxf(a, 0.f);
    }
    __syncthreads();
    if (t < MB) {
        float a = b2[0];
        #pragma unroll 10
        for (int j = 0; j < HID; ++j)
            a = fmaf(W2[j], zb[j * MB + t], a);
        out[row0 + t] = a;
    }
}

extern "C" void kernel_launch(void* const* d_in, const int* in_sizes, int n_in,
                              void* d_out, int out_size, void* d_ws, size_t ws_size,
                              hipStream_t stream) {
    const int*   x     = (const int*)  d_in[0];
    const float* embed = (const float*)d_in[1];
    const float* W_ih  = (const float*)d_in[2];
    const float* W_hh  = (const float*)d_in[3];
    const float* b_ih  = (const float*)d_in[4];
    const float* b_hh  = (const float*)d_in[5];
    const float* W1    = (const float*)d_in[6];
    const float* b1    = (const float*)d_in[7];
    const float* W2    = (const float*)d_in[8];
    const float* b2    = (const float*)d_in[9];
    float* out = (float*)d_out;

    ushort* Bm = (ushort*)d_ws;   // 256*64*2 = 32768 B scratch

    build_B<<<(256 * KP + NTHR - 1) / NTHR, NTHR, 0, stream>>>(
        embed, W_ih, W_hh, b_ih, b_hh, Bm);

    lstm4<<<NBLK, NTHR, 0, stream>>>(
        x, Bm, W1, b1, W2, b2, out);
}

// Round 5
// 692.732 us; speedup vs baseline: 1.1601x; 1.0214x over previous
//
#include <hip/hip_runtime.h>
#include <hip/hip_fp16.h>

#define T_SEQ 2048
#define HID   50
#define KP    64      // k: 0..49 = h, 50..62 = onehot, 63 = bias
#define MB    4       // batch rows per block
#define NBLK  512     // 2048 / MB -> 2 blocks/CU
#define NTHR  256     // 4 waves
#define HSTR  80      // ushorts per h row (160 B)
#define BUFB  (MB*HSTR)

#define NLOG2E  1.4426950408889634f   // gates scaled by -log2e (g-gate by -2log2e) in B
#define N2LOG2E 2.8853900817779268f

typedef __attribute__((ext_vector_type(8))) _Float16 half8;
typedef __attribute__((ext_vector_type(4))) float    f32x4;

__device__ __forceinline__ ushort f16b(float f){ return __half_as_ushort(__float2half(f)); }
__device__ __forceinline__ float rcp_(float x){ return __builtin_amdgcn_rcpf(x); }
__device__ __forceinline__ float ex2_(float x){ return __builtin_amdgcn_exp2f(x); }

// Bm[256 cols][64 k] f16.  col = w*64 + g*16 + c16 encodes unit u = w*16+c16, gate g
// (g: 0=i,1=f,2=g,3=o).  Row r = g*50+u.  ALL entries pre-scaled by -log2e (g-gate
// by -2log2e) so the MFMA emits gates in exp2 domain:
//   k<50: s*W_hh[r][k];  k in 50..62: s*embed[k-50]·W_ih[r];  k==63: s*(b_ih+b_hh)[r].
__global__ void build_B(const float* __restrict__ embed, const float* __restrict__ Wih,
                        const float* __restrict__ Whh, const float* __restrict__ bih,
                        const float* __restrict__ bhh, ushort* __restrict__ Bm) {
    int idx = blockIdx.x * blockDim.x + threadIdx.x;
    if (idx >= 256 * KP) return;
    int col = idx >> 6, k = idx & 63;
    int wq = col >> 6, g = (col >> 4) & 3, cc = col & 15;
    int u = wq * 16 + cc;
    ushort v = 0;
    if (u < HID) {
        int r = g * HID + u;
        float s = (g == 2) ? -N2LOG2E : -NLOG2E;
        if (k < HID) {
            v = f16b(s * Whh[r * HID + k]);
        } else if (k < 63) {
            float t = 0.f;
            for (int e = 0; e < HID; ++e)
                t = fmaf(embed[(k - 50) * HID + e], Wih[r * HID + e], t);
            v = f16b(s * t);
        } else {
            v = f16b(s * (bih[r] + bhh[r]));
        }
    }
    Bm[idx] = v;
}

// MB=4, 4 waves, 2 blocks/CU. A rows = h[m>>2]: lane quadrant q's accumulator regs all
// hold batch row q -> z[0] direct. Co-resident blocks are anti-phased via HW_ID wave-slot
// parity so one block's VALU phase overlaps the other's MFMA phase.
__global__ __launch_bounds__(NTHR, 2) void lstm4(
    const int*    __restrict__ x,
    const ushort* __restrict__ Bm,
    const float*  __restrict__ W1,
    const float*  __restrict__ b1,
    const float*  __restrict__ W2,
    const float*  __restrict__ b2,
    float*        __restrict__ out)
{
    const int t   = threadIdx.x;
    const int w   = t >> 6;
    const int l   = t & 63;
    const int q   = l >> 4;
    const int c16 = l & 15;
    const int u   = w * 16 + c16;          // unit handled by this lane (batch row q)
    const int wu  = __builtin_amdgcn_readfirstlane(w);   // wave-uniform wave id

    __shared__ __align__(16) ushort hbuf[2 * BUFB];   // 1280 B
    __shared__ float zb[HID * MB];

    // B fragments: wave w owns tiles 4w..4w+3 (gate j), col c16
    half8 bf[4][2];
    {
        const ushort* bp = Bm + (w * 64 + c16) * KP + q * 8;
        #pragma unroll
        for (int j = 0; j < 4; ++j) {
            bf[j][0] = *(const half8*)(bp + j * 16 * KP);
            bf[j][1] = *(const half8*)(bp + j * 16 * KP + 32);
        }
    }
    #pragma unroll
    for (int j = 0; j < 4; ++j)
        asm volatile("" : "+v"(bf[j][0]), "+v"(bf[j][1]));

    for (int i = t; i < 2 * BUFB; i += NTHR) hbuf[i] = 0;

    const int  row0 = blockIdx.x * MB;
    const int* xrow = x + (long)row0 * T_SEQ + (long)wu * T_SEQ;  // uniform -> s_load
    __syncthreads();
    int tk0 = xrow[0];
    int tk1 = xrow[1];
    if (l == 0) {
        hbuf[0 * BUFB + wu * HSTR + 63] = 0x3C00;        // bias slot = 1.0
        hbuf[1 * BUFB + wu * HSTR + 63] = 0x3C00;
        hbuf[0 * BUFB + wu * HSTR + 50 + tk0] = 0x3C00;  // onehot step 0
        hbuf[1 * BUFB + wu * HSTR + 50 + tk1] = 0x3C00;  // onehot step 1
    }
    int t0r = tk1, t1r = tk0, t2r = tk1;   // clear(t-1)/set(t+1) window (uniform)
    __syncthreads();

    // Anti-phase: the 2 co-resident blocks sit in wave slots 0/1 of each SIMD.
    // Delay slot-1 waves ~384 cyc once; blocks never mutually sync, offset persists.
    {
        uint slot = __builtin_amdgcn_s_getreg(6148) & 0xF;  // HW_ID.WAVE_ID[3:0]
        if (slot & 1) __builtin_amdgcn_s_sleep(6);
    }

    // A row m = h[m>>2]: quadrant lanes 4-lane-broadcast, 2-way banks = free
    const ushort* ar  = hbuf + (c16 >> 2) * HSTR + q * 8;
    ushort*       wr_ = hbuf + q * HSTR + u;            // h write: row q, unit u
    ushort*       hbw = hbuf + wu * HSTR + 50;          // token window base (uniform)

    float cs = 0.f;                        // cs = -2*log2e * c  (pre-scaled domain)

#define STEP(P) do {                                                              \
        int it = step + 2 + (P); if (it > T_SEQ - 1) it = T_SEQ - 1;              \
        int tknf = xrow[it];                     /* wave-uniform token prefetch */\
        half8 a0 = *(const half8*)(ar + (P) * BUFB);                              \
        half8 a1 = *(const half8*)(ar + (P) * BUFB + 32);                         \
        const f32x4 zz = {0.f, 0.f, 0.f, 0.f};                                    \
        __builtin_amdgcn_s_setprio(1);                                            \
        f32x4 z0 = __builtin_amdgcn_mfma_f32_16x16x32_f16(a0, bf[0][0], zz,0,0,0);\
        z0 = __builtin_amdgcn_mfma_f32_16x16x32_f16(a1, bf[0][1], z0, 0,0,0);     \
        f32x4 z1 = __builtin_amdgcn_mfma_f32_16x16x32_f16(a0, bf[1][0], zz,0,0,0);\
        z1 = __builtin_amdgcn_mfma_f32_16x16x32_f16(a1, bf[1][1], z1, 0,0,0);     \
        f32x4 z2 = __builtin_amdgcn_mfma_f32_16x16x32_f16(a0, bf[2][0], zz,0,0,0);\
        z2 = __builtin_amdgcn_mfma_f32_16x16x32_f16(a1, bf[2][1], z2, 0,0,0);     \
        f32x4 z3 = __builtin_amdgcn_mfma_f32_16x16x32_f16(a0, bf[3][0], zz,0,0,0);\
        z3 = __builtin_amdgcn_mfma_f32_16x16x32_f16(a1, bf[3][1], z3, 0,0,0);     \
        __builtin_amdgcn_s_setprio(0);                                            \
        /* z = -log2e*gate (g: -2log2e). clamp high side: 2^30 caps products */   \
        float pi = ex2_(fminf(z0[0], 30.f));   /* e^-gi  */                       \
        float pf = ex2_(fminf(z1[0], 30.f));   /* e^-gf  */                       \
        float qg = ex2_(fminf(z2[0], 30.f));   /* e^-2gg */                       \
        float Df = 1.f + pf;                                                      \
        float D2 = (1.f + pi) * (1.f + qg);                                       \
        float iv1 = rcp_(Df * D2);                                                \
        float fv  = iv1 * D2;                  /* sigm(gf) */                     \
        float igs = iv1 * Df * fmaf(N2LOG2E, qg, -N2LOG2E); /* -2log2e*i*g */     \
        cs = fmaf(fv, cs, igs);                                                   \
        float po = ex2_(fminf(z3[0], 30.f));   /* e^-go  */                       \
        float qc = ex2_(fminf(cs, 30.f));      /* e^-2c = 2^cs */                 \
        float iv2 = rcp_((1.f + po) * (1.f + qc));                                \
        float hh  = iv2 * (1.f - qc);          /* sigm(go)*tanh(c) */             \
        if (u < HID) wr_[(1 - (P)) * BUFB] = f16b(hh);                            \
        if (l == 0) {                                                             \
            ushort* hb = hbw + (1 - (P)) * BUFB;                                  \
            hb[t0r] = 0;                                                          \
            hb[t2r] = 0x3C00;                                                     \
        }                                                                         \
        t0r = t1r; t1r = t2r; t2r = tknf;                                         \
        __syncthreads();                                                          \
    } while (0)

    #pragma unroll 1
    for (int step = 0; step < T_SEQ; step += 2) {
        STEP(0);
        STEP(1);
    }
#undef STEP

    // Epilogue MLP: final h in buffer 0 (last step wrote it), already synced.
    if (t < MB * HID) {
        int m = t & 3, uu = t >> 2;
        float a = b1[uu];
        const ushort* hr = hbuf + m * HSTR;
        #pragma unroll 10
        for (int k = 0; k < HID; ++k)
            a = fmaf(W1[uu * HID + k], __half2float(__ushort_as_half(hr[k])), a);
        zb[uu * MB + m] = fmaxf(a, 0.f);
    }
    __syncthreads();
    if (t < MB) {
        float a = b2[0];
        #pragma unroll 10
        for (int j = 0; j < HID; ++j)
            a = fmaf(W2[j], zb[j * MB + t], a);
        out[row0 + t] = a;
    }
}

extern "C" void kernel_launch(void* const* d_in, const int* in_sizes, int n_in,
                              void* d_out, int out_size, void* d_ws, size_t ws_size,
                              hipStream_t stream) {
    const int*   x     = (const int*)  d_in[0];
    const float* embed = (const float*)d_in[1];
    const float* W_ih  = (const float*)d_in[2];
    const float* W_hh  = (const float*)d_in[3];
    const float* b_ih  = (const float*)d_in[4];
    const float* b_hh  = (const float*)d_in[5];
    const float* W1    = (const float*)d_in[6];
    const float* b1    = (const float*)d_in[7];
    const float* W2    = (const float*)d_in[8];
    const float* b2    = (const float*)d_in[9];
    float* out = (float*)d_out;

    ushort* Bm = (ushort*)d_ws;   // 256*64*2 = 32768 B scratch

    build_B<<<(256 * KP + NTHR - 1) / NTHR, NTHR, 0, stream>>>(
        embed, W_ih, W_hh, b_ih, b_hh, Bm);

    lstm4<<<NBLK, NTHR, 0, stream>>>(
        x, Bm, W1, b1, W2, b2, out);
}